// Round 11
// baseline (216.815 us; speedup 1.0000x reference)
//
#include <hip/hip_runtime.h>
#include <cmath>

// ---------------------------------------------------------------------------
// NeighborAdjustingLoss v11: v8 (best, 49.9us) + low-VGPR pipelined pass.
// v10's all-upfront loads blew the register budget (~80+ data VGPRs x3
// lambda instantiations) -> spills/occupancy loss, -35us. v11 keeps v8's
// structure exactly, changing ONLY the stream pass:
//   - groups of 2 sim float4 + 2 cent float4 (8 elems) -> ~24 live VGPRs
//   - one-group-ahead sim prefetch (loads in flight during processing)
//   - __launch_bounds__(256, 6): cap ~85 VGPR -> 6 waves/SIMD (24/CU)
// Element traversal order unchanged -> cand[] and all math bit-identical.
// B=4096, M=8192, k<=63, fp32.
// ---------------------------------------------------------------------------

#define CAPW 128   // per-wave candidate capacity (E[n]~57 @ thr 2.2)
#define MAXIT 40   // u32-key bisection bound for the rare exact fallback

__device__ inline float wave_max_f(float x) {
#pragma unroll
    for (int off = 32; off > 0; off >>= 1) x = fmaxf(x, __shfl_xor(x, off, 64));
    return x;
}
__device__ inline float wave_min_f(float x) {
#pragma unroll
    for (int off = 32; off > 0; off >>= 1) x = fminf(x, __shfl_xor(x, off, 64));
    return x;
}
__device__ inline float wave_sum_f(float x) {
#pragma unroll
    for (int off = 32; off > 0; off >>= 1) x += __shfl_xor(x, off, 64);
    return x;
}
__device__ inline unsigned int wave_min_u32(unsigned int x) {
#pragma unroll
    for (int off = 32; off > 0; off >>= 1) {
        unsigned int o = (unsigned int)__shfl_xor((int)x, off, 64);
        x = (o < x) ? o : x;
    }
    return x;
}
__device__ inline unsigned int wave_max_u32(unsigned int x) {
#pragma unroll
    for (int off = 32; off > 0; off >>= 1) {
        unsigned int o = (unsigned int)__shfl_xor((int)x, off, 64);
        x = (o > x) ? o : x;
    }
    return x;
}

// order-preserving float<->uint key
__device__ inline unsigned int f_to_key(float f) {
    unsigned int u = __float_as_uint(f);
    return u ^ ((u & 0x80000000u) ? 0xFFFFFFFFu : 0x80000000u);
}
__device__ inline float key_to_f(unsigned int key) {
    unsigned int u = key ^ ((key & 0x80000000u) ? 0x80000000u : 0xFFFFFFFFu);
    return __uint_as_float(u);
}

// bits set among lanes strictly below mine
__device__ inline unsigned int lane_prefix(unsigned long long mask) {
    return __builtin_amdgcn_mbcnt_hi((unsigned int)(mask >> 32),
           __builtin_amdgcn_mbcnt_lo((unsigned int)mask, 0u));
}

// ---- centrality = row-mean of memory bank (8 loads in flight) ----
__global__ __launch_bounds__(256)
void cent_kernel(const float* __restrict__ mem, float* __restrict__ cent, int M) {
    __shared__ float s[4];
    const int row = blockIdx.x;
    const float4* p = (const float4*)(mem + (size_t)row * M);
    const int n4 = M >> 2;
    float acc = 0.0f;
    int i = threadIdx.x;
    for (; i + 1792 < n4; i += 2048) {
        float4 q0 = p[i], q1 = p[i + 256], q2 = p[i + 512], q3 = p[i + 768];
        float4 q4 = p[i + 1024], q5 = p[i + 1280], q6 = p[i + 1536], q7 = p[i + 1792];
        acc += ((q0.x + q0.y) + (q0.z + q0.w)) + ((q1.x + q1.y) + (q1.z + q1.w))
             + ((q2.x + q2.y) + (q2.z + q2.w)) + ((q3.x + q3.y) + (q3.z + q3.w))
             + ((q4.x + q4.y) + (q4.z + q4.w)) + ((q5.x + q5.y) + (q5.z + q5.w))
             + ((q6.x + q6.y) + (q6.z + q6.w)) + ((q7.x + q7.y) + (q7.z + q7.w));
    }
    for (; i < n4; i += 256) {
        float4 q = p[i];
        acc += (q.x + q.y) + (q.z + q.w);
    }
    acc = wave_sum_f(acc);
    const int lane = threadIdx.x & 63, wid = threadIdx.x >> 6;
    if (lane == 0) s[wid] = acc;
    __syncthreads();
    if (threadIdx.x == 0) cent[row] = (s[0] + s[1] + s[2] + s[3]) / (float)M;
}

// ---- per-row loss: ONE WAVE per row, 4 rows per 256-thread block.
//      No __syncthreads. Requires B==4096, k<=63. ----
__global__ __launch_bounds__(256, 6)
void row_loss_kernel(const float* __restrict__ sim,
                     const float* __restrict__ cent,
                     const int* __restrict__ knn,
                     const float* __restrict__ temp_p,
                     float* __restrict__ per_row, int B) {
    __shared__ __align__(16) unsigned long long cand[4][CAPW];  // per-wave
    __shared__ __align__(16) unsigned long long ssel[4][64];    // per-wave

    const int tid = threadIdx.x, lane = tid & 63, wid = tid >> 6;
    const int row = (blockIdx.x << 2) + wid;
    const int   k    = knn[0];
    const float temp = temp_p[0];
    const unsigned int uk = (unsigned int)k, need = uk + 1u;

    const float4* rp = (const float4*)(sim + (size_t)row * B);
    const float4* cp = (const float4*)cent;
    unsigned long long* mycand = cand[wid];
    unsigned long long* mysel  = ssel[wid];

    float cmin, cmax, dval;
    unsigned int kmin, wcnt;

    // pipelined stream pass: groups of 2 sim float4 (+2 cent float4 JIT),
    // next group's sim loads issued BEFORE processing current group.
    // Element order identical to v8 -> bit-identical candidates.
    auto pass = [&](unsigned int kT, bool wr) {
        cmin = INFINITY; cmax = -INFINITY;
        kmin = 0xFFFFFFFFu; dval = -INFINITY; wcnt = 0u;
        float4 s0 = rp[lane], s1 = rp[64 + lane];        // group 0 prefetch
#pragma unroll
        for (int g = 0; g < 8; ++g) {
            float4 n0, n1;
            if (g < 7) {                                  // prefetch next group
                n0 = rp[(2 * g + 2) * 64 + lane];
                n1 = rp[(2 * g + 3) * 64 + lane];
            }
            const float4 c0 = cp[(2 * g) * 64 + lane];
            const float4 c1 = cp[(2 * g + 1) * 64 + lane];
            const float4 svv[2] = {s0, s1};
            const float4 cvv[2] = {c0, c1};
#pragma unroll
            for (int u = 0; u < 2; ++u) {
                const int c = 2 * g + u;
                const float tv[4] = {svv[u].x, svv[u].y, svv[u].z, svv[u].w};
                const float cw[4] = {cvv[u].x, cvv[u].y, cvv[u].z, cvv[u].w};
#pragma unroll
                for (int m = 0; m < 4; ++m) {
                    const int j = c * 256 + lane * 4 + m;
                    unsigned int key = f_to_key(tv[m]);
                    const bool isd = (j == row);
                    if (isd) { dval = tv[m]; key = 0u; }
                    else if (key < kmin) kmin = key;
                    const bool p = (key > kT);
                    const unsigned long long mask = __ballot(p);
                    if (p) {
                        if (wr) {
                            const unsigned int pos = wcnt + lane_prefix(mask);
                            if (pos < CAPW)
                                mycand[pos] = ((unsigned long long)key << 32) |
                                    (unsigned long long)(0xFFFFFFFFu - (unsigned int)j);
                        }
                    } else if (!isd) {
                        cmin = fminf(cmin, cw[m]);
                        cmax = fmaxf(cmax, cw[m]);
                    }
                    wcnt += (unsigned int)__popcll(mask);
                }
            }
            s0 = n0; s1 = n1;
        }
    };

    unsigned int keyT = f_to_key(2.2f);
    pass(keyT, true);
    unsigned int n = wcnt;                    // wave-uniform
    if (n < need || n > CAPW) {               // rare exact fallback (~5e-4/row)
        unsigned int loK = 0u, hiK = 0xFFFFFFFFu;
        for (int it = 0; it < MAXIT; ++it) {
            if (n < need) { hiK = keyT; keyT = loK + ((keyT - loK) >> 1); }
            else          { loK = keyT; keyT = keyT + ((hiK - keyT) >> 1); }
            pass(keyT, false);
            n = wcnt;
            if (n >= need && n <= CAPW) break;
        }
        pass(keyT, true);
        n = wcnt;
        if (n > CAPW) n = CAPW;               // statistical impossibility guard
    }

    // wave-reduce pass results
    const unsigned int kminb = wave_min_u32(kmin);
    const float sdiag = wave_max_f(dval);
    const float cminP = wave_min_f(cmin);
    const float cmaxP = wave_max_f(cmax);

    __builtin_amdgcn_wave_barrier();          // cand writes before rank reads

    // ---- in-wave exact all-pairs rank (n <= CAPW), fully unrolled b128 ----
    unsigned long long own = mycand[lane];    // stale if lane>=n (masked below)
    unsigned long long own2 = 0ull;
    unsigned int r = 0, r2 = 0;
    const ulonglong2* c2 = (const ulonglong2*)mycand;
    if (n <= 64u) {
#pragma unroll
        for (int o = 0; o < 32; ++o) {
            const ulonglong2 pr = c2[o];
            if ((unsigned int)(2 * o)     < n && pr.x > own) ++r;
            if ((unsigned int)(2 * o + 1) < n && pr.y > own) ++r;
        }
    } else {
        own2 = mycand[64 + lane];
#pragma unroll
        for (int o = 0; o < 64; ++o) {
            const ulonglong2 pr = c2[o];
            if ((unsigned int)(2 * o) < n) {
                if (pr.x > own)  ++r;
                if (pr.x > own2) ++r2;
            }
            if ((unsigned int)(2 * o + 1) < n) {
                if (pr.y > own)  ++r;
                if (pr.y > own2) ++r2;
            }
        }
    }

    // selected / p33 / rank-tail cent re-entry
    float cmin2 = INFINITY, cmax2 = -INFINITY;
    unsigned int p33k = 0u;
    if ((unsigned int)lane < n) {
        if (r < uk) mysel[r] = own;
        else if (r == uk) p33k = (unsigned int)(own >> 32);
        if (r >= uk) {
            const int jj = (int)(0xFFFFFFFFu - (unsigned int)own);
            const float cv = cent[jj];
            cmin2 = fminf(cmin2, cv);
            cmax2 = fmaxf(cmax2, cv);
        }
    }
    if (n > 64u) {
        const unsigned int t2 = (unsigned int)lane + 64u;
        if (t2 < n) {
            if (r2 < uk) mysel[r2] = own2;
            else if (r2 == uk) p33k = (unsigned int)(own2 >> 32);
            if (r2 >= uk) {
                const int jj = (int)(0xFFFFFFFFu - (unsigned int)own2);
                const float cv = cent[jj];
                cmin2 = fminf(cmin2, cv);
                cmax2 = fmaxf(cmax2, cv);
            }
        }
    }
    p33k  = wave_max_u32(p33k);
    cmin2 = wave_min_f(cmin2);
    cmax2 = wave_max_f(cmax2);
    __builtin_amdgcn_wave_barrier();          // mysel writes before reads

    const float mn_c = fminf(cmin2, cminP);
    const float mx_c = fmaxf(cmax2, cmaxP);
    const float mn_s = key_to_f(kminb);
    const float mx_s = key_to_f(p33k);

    // ---- finale (math identical to validated v7/v8) ----
    const bool act = (lane < k);
    const unsigned long long sel = act ? mysel[lane] : 0ull;
    const float sj = act ? key_to_f((unsigned int)(sel >> 32)) : -INFINITY;
    const int   j  = act ? (int)(0xFFFFFFFFu - (unsigned int)sel) : 0;
    const float cj = cent[j];

    float a = -INFINITY;
    if (act) {
        const float ns = (sj - mn_s) / (mx_s - mn_s);
        const float nc = (cj - mn_c) / (mx_c - mn_c);
        a = (ns - nc) * temp;
    }
    const float am   = wave_max_f(a);
    const float e    = act ? expf(a - am) : 0.0f;
    const float esum = wave_sum_f(e);
    const float pw   = e / esum;

    // m2 = max(sj) = rank-0 candidate (exact, order-free max)
    const float m2  = fmaxf(key_to_f((unsigned int)(mysel[0] >> 32)), sdiag);
    const float ex  = act ? expf(sj - m2) : 0.0f;
    const float lse = m2 + logf(wave_sum_f(ex) + expf(sdiag - m2));

    const float num = wave_sum_f(act ? pw * (sj - lse) : 0.0f) + (sdiag - lse);
    const float den = 1.0f + wave_sum_f(pw);
    if (lane == 0) per_row[row] = -num / den;
}

// ---- final mean over per_row -> out[0] ----
__global__ __launch_bounds__(256)
void reduce_kernel(const float* __restrict__ per_row, float* __restrict__ out, int B) {
    __shared__ float s[4];
    float acc = 0.0f;
    const float4* p = (const float4*)per_row;
    const int n4 = B >> 2;
    for (int i = threadIdx.x; i < n4; i += 256) {
        float4 q = p[i];
        acc += (q.x + q.y) + (q.z + q.w);
    }
    acc = wave_sum_f(acc);
    const int lane = threadIdx.x & 63, wid = threadIdx.x >> 6;
    if (lane == 0) s[wid] = acc;
    __syncthreads();
    if (threadIdx.x == 0) out[0] = (s[0] + s[1] + s[2] + s[3]) / (float)B;
}

extern "C" void kernel_launch(void* const* d_in, const int* in_sizes, int n_in,
                              void* d_out, int out_size, void* d_ws, size_t ws_size,
                              hipStream_t stream) {
    const float* sim  = (const float*)d_in[0];
    const float* mem  = (const float*)d_in[1];
    const int*   knn  = (const int*)d_in[2];
    const float* temp = (const float*)d_in[3];
    float* out     = (float*)d_out;
    float* cent    = (float*)d_ws;                 // B floats
    float* per_row = (float*)d_ws + 4096;          // B floats

    const int B = (int)(std::sqrt((double)in_sizes[0]) + 0.5);
    const int M = in_sizes[1] / B;

    cent_kernel<<<B, 256, 0, stream>>>(mem, cent, M);
    row_loss_kernel<<<B / 4, 256, 0, stream>>>(sim, cent, knn, temp, per_row, B);
    reduce_kernel<<<1, 256, 0, stream>>>(per_row, out, B);
}

// Round 12
// 49.818 us; speedup vs baseline: 4.3522x; 4.3522x over previous
//
#include <hip/hip_runtime.h>
#include <cmath>

// ---------------------------------------------------------------------------
// NeighborAdjustingLoss FINAL (= v8, best measured: 49.9us).
// Structure: 3 uniform kernels.
//  K1 cent: row-mean of 134MB memory bank, BW-bound (~20us @ ~6.7TB/s).
//  K2 row_loss: ONE WAVE PER ROW, no __syncthreads. Fused stream pass
//     (threshold-gather via ballot/mbcnt into wave-private LDS segment +
//     inline cent min/max over non-candidates), in-wave exact all-pairs
//     rank (unrolled b128 broadcast reads), wave-local finale.
//  K3 reduce: deterministic final mean.
// Post-mortem ledger (rounds 0-11): merge/tail/atomics/issue-order/barriers/
// cent-removal/deep-MLP(x2)/occupancy-cap all <=+-1us or regressed; the
// ~18us gap to the 32us BW floor is latency-bound select processing that
// cannot be hidden without register budget this envelope doesn't have
// (v10/v11: VGPR pressure -> spills, WRITE_SIZE 264MB scratch evidence).
// B=4096, M=8192, k<=63, fp32.
// ---------------------------------------------------------------------------

#define CAPW 128   // per-wave candidate capacity (E[n]~57 @ thr 2.2; P(n>128)~0)
#define MAXIT 40   // u32-key bisection bound for the rare exact fallback

__device__ inline float wave_max_f(float x) {
#pragma unroll
    for (int off = 32; off > 0; off >>= 1) x = fmaxf(x, __shfl_xor(x, off, 64));
    return x;
}
__device__ inline float wave_min_f(float x) {
#pragma unroll
    for (int off = 32; off > 0; off >>= 1) x = fminf(x, __shfl_xor(x, off, 64));
    return x;
}
__device__ inline float wave_sum_f(float x) {
#pragma unroll
    for (int off = 32; off > 0; off >>= 1) x += __shfl_xor(x, off, 64);
    return x;
}
__device__ inline unsigned int wave_min_u32(unsigned int x) {
#pragma unroll
    for (int off = 32; off > 0; off >>= 1) {
        unsigned int o = (unsigned int)__shfl_xor((int)x, off, 64);
        x = (o < x) ? o : x;
    }
    return x;
}
__device__ inline unsigned int wave_max_u32(unsigned int x) {
#pragma unroll
    for (int off = 32; off > 0; off >>= 1) {
        unsigned int o = (unsigned int)__shfl_xor((int)x, off, 64);
        x = (o > x) ? o : x;
    }
    return x;
}

// order-preserving float<->uint key
__device__ inline unsigned int f_to_key(float f) {
    unsigned int u = __float_as_uint(f);
    return u ^ ((u & 0x80000000u) ? 0xFFFFFFFFu : 0x80000000u);
}
__device__ inline float key_to_f(unsigned int key) {
    unsigned int u = key ^ ((key & 0x80000000u) ? 0x80000000u : 0xFFFFFFFFu);
    return __uint_as_float(u);
}

// bits set among lanes strictly below mine
__device__ inline unsigned int lane_prefix(unsigned long long mask) {
    return __builtin_amdgcn_mbcnt_hi((unsigned int)(mask >> 32),
           __builtin_amdgcn_mbcnt_lo((unsigned int)mask, 0u));
}

// ---- centrality = row-mean of memory bank (8 loads in flight) ----
__global__ __launch_bounds__(256)
void cent_kernel(const float* __restrict__ mem, float* __restrict__ cent, int M) {
    __shared__ float s[4];
    const int row = blockIdx.x;
    const float4* p = (const float4*)(mem + (size_t)row * M);
    const int n4 = M >> 2;
    float acc = 0.0f;
    int i = threadIdx.x;
    for (; i + 1792 < n4; i += 2048) {
        float4 q0 = p[i], q1 = p[i + 256], q2 = p[i + 512], q3 = p[i + 768];
        float4 q4 = p[i + 1024], q5 = p[i + 1280], q6 = p[i + 1536], q7 = p[i + 1792];
        acc += ((q0.x + q0.y) + (q0.z + q0.w)) + ((q1.x + q1.y) + (q1.z + q1.w))
             + ((q2.x + q2.y) + (q2.z + q2.w)) + ((q3.x + q3.y) + (q3.z + q3.w))
             + ((q4.x + q4.y) + (q4.z + q4.w)) + ((q5.x + q5.y) + (q5.z + q5.w))
             + ((q6.x + q6.y) + (q6.z + q6.w)) + ((q7.x + q7.y) + (q7.z + q7.w));
    }
    for (; i < n4; i += 256) {
        float4 q = p[i];
        acc += (q.x + q.y) + (q.z + q.w);
    }
    acc = wave_sum_f(acc);
    const int lane = threadIdx.x & 63, wid = threadIdx.x >> 6;
    if (lane == 0) s[wid] = acc;
    __syncthreads();
    if (threadIdx.x == 0) cent[row] = (s[0] + s[1] + s[2] + s[3]) / (float)M;
}

// ---- per-row loss: ONE WAVE per row, 4 rows per 256-thread block.
//      No __syncthreads. Requires B==4096, k<=63. ----
__global__ __launch_bounds__(256)
void row_loss_kernel(const float* __restrict__ sim,
                     const float* __restrict__ cent,
                     const int* __restrict__ knn,
                     const float* __restrict__ temp_p,
                     float* __restrict__ per_row, int B) {
    __shared__ __align__(16) unsigned long long cand[4][CAPW];  // per-wave
    __shared__ __align__(16) unsigned long long ssel[4][64];    // per-wave

    const int tid = threadIdx.x, lane = tid & 63, wid = tid >> 6;
    const int row = (blockIdx.x << 2) + wid;
    const int   k    = knn[0];
    const float temp = temp_p[0];
    const unsigned int uk = (unsigned int)k, need = uk + 1u;

    const float4* rp = (const float4*)(sim + (size_t)row * B);
    const float4* cp = (const float4*)cent;
    unsigned long long* mycand = cand[wid];
    unsigned long long* mysel  = ssel[wid];

    float cmin, cmax, dval;
    unsigned int kmin, wcnt;

    // fused stream pass over the row: threshold gather (optionally writing
    // candidates to the wave segment), cent min/max over non-candidates,
    // row-min key, diag value. 64 elems/lane; 8 loads in flight per group.
    auto pass = [&](unsigned int kT, bool wr) {
        cmin = INFINITY; cmax = -INFINITY;
        kmin = 0xFFFFFFFFu; dval = -INFINITY; wcnt = 0u;
        for (int g = 0; g < 4; ++g) {
            float4 sv[4], cw4[4];
#pragma unroll
            for (int u = 0; u < 4; ++u) sv[u] = rp[(g * 4 + u) * 64 + lane];
#pragma unroll
            for (int u = 0; u < 4; ++u) cw4[u] = cp[(g * 4 + u) * 64 + lane];
#pragma unroll
            for (int u = 0; u < 4; ++u) {
                const int c = g * 4 + u;
                const float tv[4] = {sv[u].x, sv[u].y, sv[u].z, sv[u].w};
                const float cw[4] = {cw4[u].x, cw4[u].y, cw4[u].z, cw4[u].w};
#pragma unroll
                for (int m = 0; m < 4; ++m) {
                    const int j = c * 256 + lane * 4 + m;
                    unsigned int key = f_to_key(tv[m]);
                    const bool isd = (j == row);
                    if (isd) { dval = tv[m]; key = 0u; }
                    else if (key < kmin) kmin = key;
                    const bool p = (key > kT);
                    const unsigned long long mask = __ballot(p);
                    if (p) {
                        if (wr) {
                            const unsigned int pos = wcnt + lane_prefix(mask);
                            if (pos < CAPW)
                                mycand[pos] = ((unsigned long long)key << 32) |
                                    (unsigned long long)(0xFFFFFFFFu - (unsigned int)j);
                        }
                    } else if (!isd) {
                        cmin = fminf(cmin, cw[m]);
                        cmax = fmaxf(cmax, cw[m]);
                    }
                    wcnt += (unsigned int)__popcll(mask);
                }
            }
        }
    };

    unsigned int keyT = f_to_key(2.2f);
    pass(keyT, true);
    unsigned int n = wcnt;                    // wave-uniform
    if (n < need || n > CAPW) {               // rare exact fallback (~5e-4/row)
        unsigned int loK = 0u, hiK = 0xFFFFFFFFu;
        for (int it = 0; it < MAXIT; ++it) {
            if (n < need) { hiK = keyT; keyT = loK + ((keyT - loK) >> 1); }
            else          { loK = keyT; keyT = keyT + ((hiK - keyT) >> 1); }
            pass(keyT, false);
            n = wcnt;
            if (n >= need && n <= CAPW) break;
        }
        pass(keyT, true);
        n = wcnt;
        if (n > CAPW) n = CAPW;               // statistical impossibility guard
    }

    // wave-reduce pass results
    const unsigned int kminb = wave_min_u32(kmin);
    const float sdiag = wave_max_f(dval);
    const float cminP = wave_min_f(cmin);
    const float cmaxP = wave_max_f(cmax);

    __builtin_amdgcn_wave_barrier();          // cand writes before rank reads

    // ---- in-wave exact all-pairs rank (n <= CAPW), fully unrolled b128 ----
    unsigned long long own = mycand[lane];    // stale if lane>=n (masked below)
    unsigned long long own2 = 0ull;
    unsigned int r = 0, r2 = 0;
    const ulonglong2* c2 = (const ulonglong2*)mycand;
    if (n <= 64u) {
#pragma unroll
        for (int o = 0; o < 32; ++o) {
            const ulonglong2 pr = c2[o];
            if ((unsigned int)(2 * o)     < n && pr.x > own) ++r;
            if ((unsigned int)(2 * o + 1) < n && pr.y > own) ++r;
        }
    } else {
        own2 = mycand[64 + lane];
#pragma unroll
        for (int o = 0; o < 64; ++o) {
            const ulonglong2 pr = c2[o];
            if ((unsigned int)(2 * o) < n) {
                if (pr.x > own)  ++r;
                if (pr.x > own2) ++r2;
            }
            if ((unsigned int)(2 * o + 1) < n) {
                if (pr.y > own)  ++r;
                if (pr.y > own2) ++r2;
            }
        }
    }

    // selected / p33 / rank-tail cent re-entry
    float cmin2 = INFINITY, cmax2 = -INFINITY;
    unsigned int p33k = 0u;
    if ((unsigned int)lane < n) {
        if (r < uk) mysel[r] = own;
        else if (r == uk) p33k = (unsigned int)(own >> 32);
        if (r >= uk) {
            const int jj = (int)(0xFFFFFFFFu - (unsigned int)own);
            const float cv = cent[jj];
            cmin2 = fminf(cmin2, cv);
            cmax2 = fmaxf(cmax2, cv);
        }
    }
    if (n > 64u) {
        const unsigned int t2 = (unsigned int)lane + 64u;
        if (t2 < n) {
            if (r2 < uk) mysel[r2] = own2;
            else if (r2 == uk) p33k = (unsigned int)(own2 >> 32);
            if (r2 >= uk) {
                const int jj = (int)(0xFFFFFFFFu - (unsigned int)own2);
                const float cv = cent[jj];
                cmin2 = fminf(cmin2, cv);
                cmax2 = fmaxf(cmax2, cv);
            }
        }
    }
    p33k  = wave_max_u32(p33k);
    cmin2 = wave_min_f(cmin2);
    cmax2 = wave_max_f(cmax2);
    __builtin_amdgcn_wave_barrier();          // mysel writes before reads

    const float mn_c = fminf(cmin2, cminP);
    const float mx_c = fmaxf(cmax2, cmaxP);
    const float mn_s = key_to_f(kminb);
    const float mx_s = key_to_f(p33k);

    // ---- finale (math identical to validated v7) ----
    const bool act = (lane < k);
    const unsigned long long sel = act ? mysel[lane] : 0ull;
    const float sj = act ? key_to_f((unsigned int)(sel >> 32)) : -INFINITY;
    const int   j  = act ? (int)(0xFFFFFFFFu - (unsigned int)sel) : 0;
    const float cj = cent[j];

    float a = -INFINITY;
    if (act) {
        const float ns = (sj - mn_s) / (mx_s - mn_s);
        const float nc = (cj - mn_c) / (mx_c - mn_c);
        a = (ns - nc) * temp;
    }
    const float am   = wave_max_f(a);
    const float e    = act ? expf(a - am) : 0.0f;
    const float esum = wave_sum_f(e);
    const float pw   = e / esum;

    // m2 = max(sj) = rank-0 candidate (exact, order-free max)
    const float m2  = fmaxf(key_to_f((unsigned int)(mysel[0] >> 32)), sdiag);
    const float ex  = act ? expf(sj - m2) : 0.0f;
    const float lse = m2 + logf(wave_sum_f(ex) + expf(sdiag - m2));

    const float num = wave_sum_f(act ? pw * (sj - lse) : 0.0f) + (sdiag - lse);
    const float den = 1.0f + wave_sum_f(pw);
    if (lane == 0) per_row[row] = -num / den;
}

// ---- final mean over per_row -> out[0] ----
__global__ __launch_bounds__(256)
void reduce_kernel(const float* __restrict__ per_row, float* __restrict__ out, int B) {
    __shared__ float s[4];
    float acc = 0.0f;
    const float4* p = (const float4*)per_row;
    const int n4 = B >> 2;
    for (int i = threadIdx.x; i < n4; i += 256) {
        float4 q = p[i];
        acc += (q.x + q.y) + (q.z + q.w);
    }
    acc = wave_sum_f(acc);
    const int lane = threadIdx.x & 63, wid = threadIdx.x >> 6;
    if (lane == 0) s[wid] = acc;
    __syncthreads();
    if (threadIdx.x == 0) out[0] = (s[0] + s[1] + s[2] + s[3]) / (float)B;
}

extern "C" void kernel_launch(void* const* d_in, const int* in_sizes, int n_in,
                              void* d_out, int out_size, void* d_ws, size_t ws_size,
                              hipStream_t stream) {
    const float* sim  = (const float*)d_in[0];
    const float* mem  = (const float*)d_in[1];
    const int*   knn  = (const int*)d_in[2];
    const float* temp = (const float*)d_in[3];
    float* out     = (float*)d_out;
    float* cent    = (float*)d_ws;                 // B floats
    float* per_row = (float*)d_ws + 4096;          // B floats

    const int B = (int)(std::sqrt((double)in_sizes[0]) + 0.5);
    const int M = in_sizes[1] / B;

    cent_kernel<<<B, 256, 0, stream>>>(mem, cent, M);
    row_loss_kernel<<<B / 4, 256, 0, stream>>>(sim, cent, knn, temp, per_row, B);
    reduce_kernel<<<1, 256, 0, stream>>>(per_row, out, B);
}